// Round 1
// baseline (139.763 us; speedup 1.0000x reference)
//
#include <hip/hip_runtime.h>
#include <math.h>

#define IN_DIM  768
#define OUT_DIM 768
#define BATCH   32
#define NUM_F   8

#define O_TILE  16                    // outputs per block
#define I_CHUNK 32                    // inputs per block
#define I_SPLIT (IN_DIM / I_CHUNK)    // 24 blocks along i

// LDS basis layout: S[j][b][il] with il-stride padded to 33 floats.
//  - phase-1 writes: lanes have consecutive il -> consecutive addresses, conflict-free
//  - phase-2 reads:  lanes have consecutive b  -> bank (33*b+il)%32 = (b+il)%32, all 32 banks
#define SROW   (I_CHUNK + 1)          // 33
#define SPLANE (BATCH * SROW)         // 1056 floats per j-plane
#define SMEM_FLOATS (9 * SPLANE)      // 9504 floats = 38016 B -> 4 blocks/CU (152 KB of 160 KB)

// Seed y[b][o] = bias_w[o]. 32 blocks x 768 threads, fully coalesced.
__global__ __launch_bounds__(768) void init_y(const float* __restrict__ bias_w,
                                              float* __restrict__ y) {
    y[blockIdx.x * OUT_DIM + threadIdx.x] = bias_w[threadIdx.x];
}

// One fused kernel: build sin/silu basis for an i-chunk in LDS, stream coef/scales
// exactly once, reduce across i-groups in LDS, atomicAdd partial into y.
__global__ __launch_bounds__(256) void fused(const float* __restrict__ x,
                                             const float* __restrict__ grid,
                                             const float* __restrict__ coef,
                                             const float* __restrict__ scale_base,
                                             const float* __restrict__ scale_sp,
                                             float* __restrict__ y) {
    __shared__ float smem[SMEM_FLOATS];   // reused: phase 1/2 = basis, phase 3 = reduce

    const int t  = threadIdx.x;
    const int is = blockIdx.x;            // 0..23  i-chunk
    const int ob = blockIdx.y;            // 0..47  o-tile
    const int i0 = is * I_CHUNK;
    const int o0 = ob * O_TILE;

    // ---- Phase 1: basis into LDS ----
    float gv[NUM_F];
#pragma unroll
    for (int j = 0; j < NUM_F; ++j) gv[j] = grid[j];

#pragma unroll
    for (int p = t; p < BATCH * I_CHUNK; p += 256) {   // 4 iterations
        const int il = p & (I_CHUNK - 1);
        const int b  = p >> 5;
        const float xv = x[b * IN_DIM + i0 + il];      // lanes: il consecutive -> coalesced
#pragma unroll
        for (int j = 0; j < NUM_F; ++j)
            smem[j * SPLANE + b * SROW + il] = __sinf(gv[j] * xv);
        smem[8 * SPLANE + b * SROW + il] = xv / (1.0f + __expf(-xv));  // silu
    }
    __syncthreads();

    // ---- Phase 2: stream coef / scales, accumulate ----
    const int b = t & 31;                 // batch lane
    const int g = t >> 5;                 // i-group 0..7
    float acc[O_TILE];
#pragma unroll
    for (int ol = 0; ol < O_TILE; ++ol) acc[ol] = 0.0f;

#pragma unroll
    for (int k = 0; k < I_CHUNK / 8; ++k) {            // 4 iterations
        const int il = g + k * 8;
        const int i  = i0 + il;
        float s[9];
#pragma unroll
        for (int j = 0; j < 9; ++j) s[j] = smem[j * SPLANE + b * SROW + il];
#pragma unroll
        for (int ol = 0; ol < O_TILE; ++ol) {
            const size_t n = (size_t)(o0 + ol) * IN_DIM + i;   // uniform per half-wave
            const float4 c0 = *(const float4*)(coef + n * 8);
            const float4 c1 = *(const float4*)(coef + n * 8 + 4);
            const float ssp = scale_sp[n];
            const float sb  = scale_base[n];
            const float dot = c0.x * s[0] + c0.y * s[1] + c0.z * s[2] + c0.w * s[3]
                            + c1.x * s[4] + c1.y * s[5] + c1.z * s[6] + c1.w * s[7];
            acc[ol] += ssp * dot + sb * s[8];
        }
    }

    __syncthreads();                      // all basis reads done; smem now reduce buffer

    // ---- Phase 3: reduce across the 8 i-groups, one atomic per (b,ol) ----
    // layout [g][ol][b]: lane stride 1 in b -> conflict-free stores and loads
#pragma unroll
    for (int ol = 0; ol < O_TILE; ++ol)
        smem[(g * O_TILE + ol) * 32 + b] = acc[ol];
    __syncthreads();

#pragma unroll
    for (int rep = 0; rep < 2; ++rep) {
        const int idx2 = t + rep * 256;   // 0..511 = (ol2, b2)
        const int b2  = idx2 & 31;
        const int ol2 = idx2 >> 5;
        float sum = 0.0f;
#pragma unroll
        for (int g2 = 0; g2 < 8; ++g2) sum += smem[(g2 * O_TILE + ol2) * 32 + b2];
        atomicAdd(&y[b2 * OUT_DIM + o0 + ol2], sum);
    }
}

extern "C" void kernel_launch(void* const* d_in, const int* in_sizes, int n_in,
                              void* d_out, int out_size, void* d_ws, size_t ws_size,
                              hipStream_t stream) {
    const float* x          = (const float*)d_in[0];  // 32*12*64
    const float* grid       = (const float*)d_in[1];  // 8
    const float* coef       = (const float*)d_in[2];  // 589824*8
    const float* bias_w     = (const float*)d_in[3];  // 768
    const float* scale_base = (const float*)d_in[4];  // 589824
    const float* scale_sp   = (const float*)d_in[5];  // 589824
    float* y = (float*)d_out;                         // 32*768
    (void)d_ws; (void)ws_size;                        // workspace intentionally unused

    init_y<<<BATCH, OUT_DIM, 0, stream>>>(bias_w, y);
    dim3 grid2(I_SPLIT, OUT_DIM / O_TILE);            // 24 x 48 = 1152 blocks
    fused<<<grid2, 256, 0, stream>>>(x, grid, coef, scale_base, scale_sp, y);
}

// Round 2
// 106.508 us; speedup vs baseline: 1.3122x; 1.3122x over previous
//
#include <hip/hip_runtime.h>
#include <math.h>

#define IN_DIM  768
#define OUT_DIM 768
#define BATCH   32
#define NUM_F   8

#define O_TILE  16                    // outputs per block
#define I_CHUNK 32                    // inputs per block
#define I_SPLIT (IN_DIM / I_CHUNK)    // 24

// LDS: coef tile [O_TILE][I_CHUNK][8] = 4096 floats (16 KB)
//      ssp tile  [O_TILE][I_CHUNK]    =  512 floats (2 KB)
//      sb  tile  [O_TILE][I_CHUNK]    =  512 floats (2 KB)
// total 20 KB -> 8 blocks/CU by LDS; VGPR (~80) limits to ~4 blocks/CU.
#define C_FLOATS    (O_TILE * I_CHUNK * 8)     // 4096
#define SSP_OFF     C_FLOATS                   // 4096
#define SB_OFF      (C_FLOATS + 512)           // 4608
#define SMEM_FLOATS (C_FLOATS + 1024)          // 5120 floats = 20 KB

__device__ __forceinline__ void gload_lds16(const void* g, void* l) {
    __builtin_amdgcn_global_load_lds(
        (const __attribute__((address_space(1))) void*)g,
        (__attribute__((address_space(3))) void*)l, 16, 0, 0);
}
__device__ __forceinline__ void gload_lds4(const void* g, void* l) {
    __builtin_amdgcn_global_load_lds(
        (const __attribute__((address_space(1))) void*)g,
        (__attribute__((address_space(3))) void*)l, 4, 0, 0);
}

// Seed y[b][o] = bias_w[o]. 24576 elements, 96 blocks x 256.
__global__ __launch_bounds__(256) void init_y(const float* __restrict__ bias_w,
                                              float* __restrict__ y) {
    const int gid = blockIdx.x * 256 + threadIdx.x;
    y[gid] = bias_w[gid % OUT_DIM];
}

__global__ __launch_bounds__(256, 4) void fused(const float* __restrict__ x,
                                                const float* __restrict__ grid,
                                                const float* __restrict__ coef,
                                                const float* __restrict__ scale_base,
                                                const float* __restrict__ scale_sp,
                                                float* __restrict__ y) {
    __shared__ float smem[SMEM_FLOATS];

    const int t  = threadIdx.x;
    const int is = blockIdx.x;            // 0..23  i-chunk
    const int ob = blockIdx.y;            // 0..47  o-tile
    const int i0 = is * I_CHUNK;
    const int o0 = ob * O_TILE;

    // ---- Phase 0: issue async coef/scale staging (global -> LDS, coalesced) ----
    {
        const char* cbase = (const char*)coef;
#pragma unroll
        for (int r = 0; r < 4; ++r) {
            const int q   = r * 256 + t;          // 16B-chunk id, 0..1023
            const int ol  = q >> 6;               // constant per wave
            const int rem = (q & 63) << 4;        // byte offset within ol's 1KB row-pack
            const char* gp = cbase + (size_t)(o0 + ol) * (IN_DIM * 32)
                                   + (size_t)i0 * 32 + rem;
            gload_lds16(gp, (char*)smem + (size_t)q * 16);
        }
#pragma unroll
        for (int r = 0; r < 2; ++r) {
            const int p  = r * 256 + t;           // 0..511
            const int ol = p >> 5;
            const int il = p & 31;
            const size_t n = (size_t)(o0 + ol) * IN_DIM + i0 + il;
            gload_lds4(scale_sp   + n, smem + SSP_OFF + p);
            gload_lds4(scale_base + n, smem + SB_OFF  + p);
        }
    }

    // ---- Phase 1: per-thread basis in REGISTERS (overlaps the async staging) ----
    const int b = t & 31;                 // batch lane
    const int g = t >> 5;                 // i-group 0..7  (il = g + 8k)
    float gv[NUM_F];
#pragma unroll
    for (int j = 0; j < NUM_F; ++j) gv[j] = grid[j];

    float s[4][9];
#pragma unroll
    for (int k = 0; k < 4; ++k) {
        const float xv = x[b * IN_DIM + i0 + g + 8 * k];
#pragma unroll
        for (int j = 0; j < NUM_F; ++j) s[k][j] = __sinf(gv[j] * xv);
        s[k][8] = xv / (1.0f + __expf(-xv));      // silu
    }

    asm volatile("s_waitcnt vmcnt(0)" ::: "memory");
    __syncthreads();

    // ---- Phase 2: all-LDS/register main loop (no global ops) ----
    float acc[O_TILE];
#pragma unroll
    for (int ol = 0; ol < O_TILE; ++ol) acc[ol] = 0.0f;

#pragma unroll
    for (int k = 0; k < 4; ++k) {
        const int il = g + 8 * k;
        const float* cp = smem + il * 8;          // + ol*256 gives [ol][il][0]
#pragma unroll
        for (int ol = 0; ol < O_TILE; ++ol) {
            const float4 c0 = *(const float4*)(cp + ol * 256);
            const float4 c1 = *(const float4*)(cp + ol * 256 + 4);
            const float ssp = smem[SSP_OFF + ol * 32 + il];
            const float sb  = smem[SB_OFF  + ol * 32 + il];
            const float dot = c0.x * s[k][0] + c0.y * s[k][1]
                            + c0.z * s[k][2] + c0.w * s[k][3]
                            + c1.x * s[k][4] + c1.y * s[k][5]
                            + c1.z * s[k][6] + c1.w * s[k][7];
            acc[ol] += ssp * dot + sb * s[k][8];
        }
    }

    __syncthreads();                      // phase-2 reads done; smem becomes reduce buffer

    // ---- Phase 3: reduce across the 8 i-groups, 2 atomics per thread ----
    // layout [g][ol][b]: lane stride 1 in b -> conflict-free both directions
#pragma unroll
    for (int ol = 0; ol < O_TILE; ++ol)
        smem[(g * O_TILE + ol) * 32 + b] = acc[ol];
    __syncthreads();

#pragma unroll
    for (int rep = 0; rep < 2; ++rep) {
        const int idx2 = t + rep * 256;   // 0..511 = (ol2, b2)
        const int b2  = idx2 & 31;
        const int ol2 = idx2 >> 5;
        float sum = 0.0f;
#pragma unroll
        for (int g2 = 0; g2 < 8; ++g2) sum += smem[(g2 * O_TILE + ol2) * 32 + b2];
        atomicAdd(&y[b2 * OUT_DIM + o0 + ol2], sum);
    }
}

extern "C" void kernel_launch(void* const* d_in, const int* in_sizes, int n_in,
                              void* d_out, int out_size, void* d_ws, size_t ws_size,
                              hipStream_t stream) {
    const float* x          = (const float*)d_in[0];  // 32*12*64
    const float* grid       = (const float*)d_in[1];  // 8
    const float* coef       = (const float*)d_in[2];  // 589824*8
    const float* bias_w     = (const float*)d_in[3];  // 768
    const float* scale_base = (const float*)d_in[4];  // 589824
    const float* scale_sp   = (const float*)d_in[5];  // 589824
    float* y = (float*)d_out;                         // 32*768
    (void)d_ws; (void)ws_size;                        // workspace intentionally unused

    init_y<<<(BATCH * OUT_DIM) / 256, 256, 0, stream>>>(bias_w, y);
    dim3 grid2(I_SPLIT, OUT_DIM / O_TILE);            // 24 x 48 = 1152 blocks
    fused<<<grid2, 256, 0, stream>>>(x, grid, coef, scale_base, scale_sp, y);
}

// Round 3
// 90.076 us; speedup vs baseline: 1.5516x; 1.1824x over previous
//
#include <hip/hip_runtime.h>
#include <math.h>

#define IN_DIM  768
#define OUT_DIM 768
#define BATCH   32
#define NUM_F   8

#define O_TILE  16                    // outputs per block
#define I_CHUNK 32                    // inputs per block
#define I_SPLIT (IN_DIM / I_CHUNK)    // 24

// LDS: coef tile [O_TILE][I_CHUNK][8] = 4096 floats (16 KB)
//      ssp tile  [O_TILE][8 g][4 k]  =  512 floats (2 KB)   (k contiguous -> b128 reads)
//      sb  tile  [O_TILE][8 g][4 k]  =  512 floats (2 KB)
// total 20 KB. VGPR ~64 -> 8 blocks/CU (LDS-limited), full occupancy.
#define C_FLOATS    (O_TILE * I_CHUNK * 8)     // 4096
#define SSP_OFF     C_FLOATS                   // 4096
#define SB_OFF      (C_FLOATS + 512)           // 4608
#define SMEM_FLOATS (C_FLOATS + 1024)          // 5120 floats = 20 KB

__device__ __forceinline__ void gload_lds16(const void* g, void* l) {
    __builtin_amdgcn_global_load_lds(
        (const __attribute__((address_space(1))) void*)g,
        (__attribute__((address_space(3))) void*)l, 16, 0, 0);
}
__device__ __forceinline__ void gload_lds4(const void* g, void* l) {
    __builtin_amdgcn_global_load_lds(
        (const __attribute__((address_space(1))) void*)g,
        (__attribute__((address_space(3))) void*)l, 4, 0, 0);
}

// Seed y[b][o] = bias_w[o]. 96 blocks x 256, coalesced.
__global__ __launch_bounds__(256) void init_y(const float* __restrict__ bias_w,
                                              float* __restrict__ y) {
    const int gid = blockIdx.x * 256 + threadIdx.x;
    y[gid] = bias_w[gid % OUT_DIM];
}

__global__ __launch_bounds__(256, 4) void fused(const float* __restrict__ x,
                                                const float* __restrict__ grid,
                                                const float* __restrict__ coef,
                                                const float* __restrict__ scale_base,
                                                const float* __restrict__ scale_sp,
                                                float* __restrict__ y) {
    __shared__ float smem[SMEM_FLOATS];

    const int t  = threadIdx.x;
    const int is = blockIdx.x;            // 0..23  i-chunk
    const int ob = blockIdx.y;            // 0..47  o-tile
    const int i0 = is * I_CHUNK;
    const int o0 = ob * O_TILE;

    // ---- Phase 0: issue async coef/scale staging (global -> LDS) ----
    {
        const char* cbase = (const char*)coef;
#pragma unroll
        for (int r = 0; r < 4; ++r) {
            const int q   = r * 256 + t;          // 16B-chunk id, 0..1023
            const int ol  = q >> 6;
            const int rem = (q & 63) << 4;        // bytes within this ol's 1KB slab
            const char* gp = cbase + (size_t)(o0 + ol) * (IN_DIM * 32)
                                   + (size_t)i0 * 32 + rem;
            gload_lds16(gp, (char*)smem + (size_t)q * 16);
        }
        // scales staged PERMUTED: LDS slot p = ol*32 + g*4 + k  <->  i = i0 + g + 8k.
        // This makes k=0..3 contiguous so phase 2 reads them as one float4.
#pragma unroll
        for (int r = 0; r < 2; ++r) {
            const int p  = r * 256 + t;           // 0..511
            const int ol = p >> 5;
            const int gg = (p >> 2) & 7;
            const int kk = p & 3;
            const size_t n = (size_t)(o0 + ol) * IN_DIM + i0 + gg + 8 * kk;
            gload_lds4(scale_sp   + n, smem + SSP_OFF + p);
            gload_lds4(scale_base + n, smem + SB_OFF  + p);
        }
    }

    // ---- Phase 1: per-thread basis in registers (overlaps staging) ----
    const int b = t & 31;                 // batch lane
    const int g = t >> 5;                 // i-group 0..7  (il = g + 8k)
    float gv[NUM_F];
#pragma unroll
    for (int j = 0; j < NUM_F; ++j) gv[j] = grid[j];

    float s[4][9];
#pragma unroll
    for (int k = 0; k < 4; ++k) {
        const float xv = x[b * IN_DIM + i0 + g + 8 * k];
#pragma unroll
        for (int j = 0; j < NUM_F; ++j) s[k][j] = __sinf(gv[j] * xv);
        s[k][8] = xv / (1.0f + __expf(-xv));      // silu
    }

    asm volatile("s_waitcnt vmcnt(0)" ::: "memory");
    __syncthreads();

    // ---- Phase 2: all-LDS/register main loop ----
    float acc[O_TILE];
    const int gb = g << 2;                // g*4: scale-vector base
#pragma unroll
    for (int ol = 0; ol < O_TILE; ++ol) {
        const float4 ssp4 = *(const float4*)(smem + SSP_OFF + ol * 32 + gb);
        const float4 sb4  = *(const float4*)(smem + SB_OFF  + ol * 32 + gb);
        const float* cp = smem + ol * 256 + g * 8;    // [ol][il=g][j=0]
        float a = 0.0f;
#pragma unroll
        for (int k = 0; k < 4; ++k) {                 // il = g + 8k -> +64 floats/k
            const float4 c0 = *(const float4*)(cp + 64 * k);
            const float4 c1 = *(const float4*)(cp + 64 * k + 4);
            const float dot = c0.x * s[k][0] + c0.y * s[k][1]
                            + c0.z * s[k][2] + c0.w * s[k][3]
                            + c1.x * s[k][4] + c1.y * s[k][5]
                            + c1.z * s[k][6] + c1.w * s[k][7];
            a += (&ssp4.x)[k] * dot + (&sb4.x)[k] * s[k][8];
        }
        acc[ol] = a;
    }

    __syncthreads();                      // phase-2 reads done; smem becomes reduce buffer

    // ---- Phase 3: reduce across 8 i-groups; coalesced atomics ----
    // buffer [g][b][17]: writes (lanes vary b, stride 17) conflict-free;
    // reads (lanes vary ol,b2) <=3-way; atomics: lanes consecutive in o -> ~4 lines/instr.
#pragma unroll
    for (int ol = 0; ol < O_TILE; ++ol)
        smem[(g * 32 + b) * 17 + ol] = acc[ol];
    __syncthreads();

#pragma unroll
    for (int rep = 0; rep < 2; ++rep) {
        const int idx2 = t + rep * 256;   // 0..511
        const int b2  = idx2 >> 4;        // 0..31
        const int ol2 = idx2 & 15;        // consecutive across lanes
        float sum = 0.0f;
#pragma unroll
        for (int g2 = 0; g2 < 8; ++g2) sum += smem[(g2 * 32 + b2) * 17 + ol2];
        atomicAdd(&y[b2 * OUT_DIM + o0 + ol2], sum);
    }
}

extern "C" void kernel_launch(void* const* d_in, const int* in_sizes, int n_in,
                              void* d_out, int out_size, void* d_ws, size_t ws_size,
                              hipStream_t stream) {
    const float* x          = (const float*)d_in[0];  // 32*12*64
    const float* grid       = (const float*)d_in[1];  // 8
    const float* coef       = (const float*)d_in[2];  // 589824*8
    const float* bias_w     = (const float*)d_in[3];  // 768
    const float* scale_base = (const float*)d_in[4];  // 589824
    const float* scale_sp   = (const float*)d_in[5];  // 589824
    float* y = (float*)d_out;                         // 32*768
    (void)d_ws; (void)ws_size;                        // workspace intentionally unused

    init_y<<<(BATCH * OUT_DIM) / 256, 256, 0, stream>>>(bias_w, y);
    dim3 grid2(I_SPLIT, OUT_DIM / O_TILE);            // 24 x 48 = 1152 blocks
    fused<<<grid2, 256, 0, stream>>>(x, grid, coef, scale_base, scale_sp, y);
}